// Round 9
// baseline (7559.975 us; speedup 1.0000x reference)
//
#include <hip/hip_runtime.h>
#include <hip/hip_bf16.h>

typedef __hip_bfloat16 bf16;
typedef __attribute__((ext_vector_type(8))) short short8;
typedef __attribute__((ext_vector_type(4))) float floatx4;

constexpr int Nn = 100000;   // nodes
constexpr int Ee = 640000;   // edges
constexpr int Pp = 640000;   // pos entries
constexpr int Gg = 128;      // graphs
constexpr int Ll = 3;        // layers
#define Dd 128
#define BN_EPS 1e-5f

__device__ __forceinline__ float b2f(bf16 x) { return __bfloat162float(x); }
__device__ __forceinline__ bf16 f2b(float x) { return __float2bfloat16(x); }

union U8 { uint4 u; bf16 h[8]; };

__device__ __forceinline__ float bnf(float x, float g, float b, float m, float v) {
  return (x - m) * (1.0f / sqrtf(v + BN_EPS)) * g + b;
}

// -------- estart[e] = lower_bound(pos_batch, e) --------
__global__ void k_estart(const int* __restrict__ pos_batch, int* __restrict__ estart) {
  int e = blockIdx.x * blockDim.x + threadIdx.x;
  if (e > Ee) return;
  int lo = 0, hi = Pp;
  while (lo < hi) { int mid = (lo + hi) >> 1; if (pos_batch[mid] < e) lo = mid + 1; else hi = mid; }
  estart[e] = lo;
}

// -------- pre-swizzle weights into MFMA B-fragment order: [kc][t][lane][8] --------
__global__ void k_prep(const float* __restrict__ zeW, const float* __restrict__ Wp,
                       const float* __restrict__ We, const float* __restrict__ be,
                       const float* __restrict__ bp,
                       const float* __restrict__ W1, const float* __restrict__ W2,
                       bf16* __restrict__ zeWsw, bf16* __restrict__ WpSw,
                       bf16* __restrict__ WeSw, bf16* __restrict__ W1sw,
                       bf16* __restrict__ W2sw) {
  int gid = blockIdx.x * blockDim.x + threadIdx.x;
  if (gid < 16384) {
    int i = gid;
    int j = i & 7, lane = (i >> 3) & 63, t = (i >> 9) & 7, kc = i >> 12;
    int k = kc * 32 + ((lane >> 4) * 8) + j, n = t * 16 + (lane & 15);
    zeWsw[i] = f2b(zeW[k * 128 + n]);
  }
  if (gid < 49152) {
    int l = gid / 16384, i = gid % 16384;
    int j = i & 7, lane = (i >> 3) & 63, t = (i >> 9) & 7, kc = i >> 12;
    int k = kc * 32 + ((lane >> 4) * 8) + j, n = t * 16 + (lane & 15);
    WpSw[gid] = f2b(Wp[l * 16384 + k * 128 + n]);
  }
  if (gid < 12288) {
    int l = gid / 4096, i = gid % 4096;
    int j = i & 7, lane = (i >> 3) & 63, t = i >> 9;
    int k = ((lane >> 4) * 8) + j, n = t * 16 + (lane & 15);
    float v = 0.f;
    if (k < 7) v = We[l * 896 + k * 128 + n];
    else if (k == 7) v = be[l * 128 + n] + bp[l * 128 + n];
    WeSw[gid] = f2b(v);
  }
  if (gid < 98304) {
    int l = gid / 32768, i = gid % 32768;
    int j = i & 7, lane = (i >> 3) & 63, t = (i >> 9) & 15, kc = i >> 13;
    int k = kc * 32 + ((lane >> 4) * 8) + j, n = t * 16 + (lane & 15);
    W1sw[gid] = f2b(W1[l * 32768 + k * 256 + n]);
  }
  if (gid < 98304) {
    int l = gid / 32768, i = gid % 32768;
    int j = i & 7, lane = (i >> 3) & 63, t = (i >> 9) & 7, kc = i >> 12;
    int k = kc * 32 + ((lane >> 4) * 8) + j, n = t * 16 + (lane & 15);
    W2sw[gid] = f2b(W2[l * 32768 + k * 128 + n]);
  }
}

__global__ void k_init_vn(const float* __restrict__ vn_emb, float* __restrict__ vn) {
  int gid = blockIdx.x * blockDim.x + threadIdx.x;
  if (gid >= Gg * 128) return;
  vn[gid] = vn_emb[gid & 127];
}

// -------- h_in = node_emb[x_node] + vn[batch]  (layer 0) --------
__global__ void k_hin0(const int* __restrict__ x_node, const float* __restrict__ node_emb,
                       const float* __restrict__ vn, const int* __restrict__ batch,
                       bf16* __restrict__ h_in) {
  int gid = blockIdx.x * blockDim.x + threadIdx.x;
  if (gid >= Nn * 16) return;
  int n = gid >> 4, c = gid & 15;
  int x = x_node[n], b = batch[n];
  float4 a0 = ((const float4*)node_emb)[x * 32 + c * 2];
  float4 a1 = ((const float4*)node_emb)[x * 32 + c * 2 + 1];
  float4 v0 = ((const float4*)vn)[b * 32 + c * 2];
  float4 v1 = ((const float4*)vn)[b * 32 + c * 2 + 1];
  U8 o;
  o.h[0] = f2b(a0.x + v0.x); o.h[1] = f2b(a0.y + v0.y);
  o.h[2] = f2b(a0.z + v0.z); o.h[3] = f2b(a0.w + v0.w);
  o.h[4] = f2b(a1.x + v1.x); o.h[5] = f2b(a1.y + v1.y);
  o.h[6] = f2b(a1.z + v1.z); o.h[7] = f2b(a1.w + v1.w);
  ((uint4*)h_in)[gid] = o.u;
}

// -------- h_in += vn[batch]  (layers 1..) --------
__global__ void k_hin(const float* __restrict__ vn, const int* __restrict__ batch,
                      bf16* __restrict__ h_in) {
  int gid = blockIdx.x * blockDim.x + threadIdx.x;
  if (gid >= Nn * 16) return;
  int n = gid >> 4, c = gid & 15;
  U8 a; a.u = ((const uint4*)h_in)[gid];
  int b = batch[n];
  float4 v0 = ((const float4*)vn)[b * 32 + c * 2];
  float4 v1 = ((const float4*)vn)[b * 32 + c * 2 + 1];
  U8 o;
  o.h[0] = f2b(b2f(a.h[0]) + v0.x); o.h[1] = f2b(b2f(a.h[1]) + v0.y);
  o.h[2] = f2b(b2f(a.h[2]) + v0.z); o.h[3] = f2b(b2f(a.h[3]) + v0.w);
  o.h[4] = f2b(b2f(a.h[4]) + v1.x); o.h[5] = f2b(b2f(a.h[5]) + v1.y);
  o.h[6] = f2b(b2f(a.h[6]) + v1.z); o.h[7] = f2b(b2f(a.h[7]) + v1.w);
  ((uint4*)h_in)[gid] = o.u;
}

// -------- fused edge kernel: MFMA + in-Az bf16 transpose + coalesced f32 atomics ----
__global__ __launch_bounds__(256, 4) void k_edge_fused(
    const int* __restrict__ estart, const int* __restrict__ pos_index,
    const float* __restrict__ pos_enc, const float* __restrict__ z_init,
    const float* __restrict__ ze_bn1, const bf16* __restrict__ zeWsw,
    const float* __restrict__ ze_b, const float* __restrict__ ze_bn2,
    const float* __restrict__ eattr, const int* __restrict__ src,
    const int* __restrict__ dst, const bf16* __restrict__ h_in,
    const bf16* __restrict__ WpSw, const bf16* __restrict__ WeSw,
    float* __restrict__ agg) {
  __shared__ bf16 Az[64][136];   // wave-exclusive rows 16wv..16wv+15 (zpool -> z -> msg)
  __shared__ bf16 EaB[64][40];
  int tid = threadIdx.x;
  int lane = tid & 63, wv = tid >> 6;
  int q = lane >> 4, ln = lane & 15;
  int e0 = blockIdx.x * 64;

  // ---- stage EaB (wave-exclusive rows)
  {
    int r = lane >> 2, c0 = (lane & 3) * 8;
    int e = e0 + 16 * wv + r;
    U8 o;
    #pragma unroll
    for (int j = 0; j < 8; ++j) {
      int c = c0 + j;
      float v = 0.f;
      if (c < 7) v = eattr[(size_t)e * 7 + c];
      else if (c == 7) v = 1.0f;
      o.h[j] = f2b(v);
    }
    *(uint4*)&EaB[16 * wv + r][c0] = o.u;
  }
  // ---- zpool gather + bn1/relu -> Az (wave-exclusive rows)
  {
    int r = lane >> 2, cc = lane & 3;
    int e = e0 + 16 * wv + r;
    int ps = estart[e], pe = estart[e + 1];
    float acc[32];
    #pragma unroll
    for (int j = 0; j < 32; ++j) acc[j] = 0.f;
    for (int p = ps; p < pe; ++p) {
      int idx = pos_index[p];
      float w = pos_enc[p];
      #pragma unroll
      for (int qq = 0; qq < 8; ++qq) {
        float4 z4 = ((const float4*)z_init)[idx * 32 + cc * 8 + qq];
        acc[qq * 4 + 0] = fmaf(w, z4.x, acc[qq * 4 + 0]);
        acc[qq * 4 + 1] = fmaf(w, z4.y, acc[qq * 4 + 1]);
        acc[qq * 4 + 2] = fmaf(w, z4.z, acc[qq * 4 + 2]);
        acc[qq * 4 + 3] = fmaf(w, z4.w, acc[qq * 4 + 3]);
      }
    }
    #pragma unroll
    for (int qq = 0; qq < 4; ++qq) {
      U8 o;
      #pragma unroll
      for (int jj = 0; jj < 2; ++jj) {
        int col = cc * 32 + qq * 8 + jj * 4;
        float4 g = *(const float4*)&ze_bn1[col];
        float4 b = *(const float4*)&ze_bn1[128 + col];
        float4 m = *(const float4*)&ze_bn1[256 + col];
        float4 v = *(const float4*)&ze_bn1[384 + col];
        o.h[jj * 4 + 0] = f2b(fmaxf(0.f, bnf(acc[qq * 8 + jj * 4 + 0], g.x, b.x, m.x, v.x)));
        o.h[jj * 4 + 1] = f2b(fmaxf(0.f, bnf(acc[qq * 8 + jj * 4 + 1], g.y, b.y, m.y, v.y)));
        o.h[jj * 4 + 2] = f2b(fmaxf(0.f, bnf(acc[qq * 8 + jj * 4 + 2], g.z, b.z, m.z, v.z)));
        o.h[jj * 4 + 3] = f2b(fmaxf(0.f, bnf(acc[qq * 8 + jj * 4 + 3], g.w, b.w, m.w, v.w)));
      }
      *(uint4*)&Az[16 * wv + r][cc * 32 + qq * 8] = o.u;
    }
  }
  __builtin_amdgcn_wave_barrier();

  // ---- GEMM0: acc2 = EaB @ WeSw (K=32 incl. bias col)
  floatx4 acc2[8] = {};
  {
    short8 af0 = *(const short8*)&EaB[16 * wv + ln][q * 8];
    #pragma unroll
    for (int t = 0; t < 8; ++t) {
      short8 bfr = *(const short8*)(WeSw + ((size_t)t * 64 + lane) * 8);
      acc2[t] = __builtin_amdgcn_mfma_f32_16x16x32_bf16(af0, bfr, acc2[t], 0, 0, 0);
    }
  }
  // ---- GEMM1: acc1 = Az @ zeWsw
  floatx4 acc1[8] = {};
  #pragma unroll
  for (int kc = 0; kc < 4; ++kc) {
    short8 af = *(const short8*)&Az[16 * wv + ln][kc * 32 + q * 8];
    #pragma unroll
    for (int t = 0; t < 8; ++t) {
      short8 bfr = *(const short8*)(zeWsw + (((size_t)kc * 8 + t) * 64 + lane) * 8);
      acc1[t] = __builtin_amdgcn_mfma_f32_16x16x32_bf16(af, bfr, acc1[t], 0, 0, 0);
    }
  }
  // ---- z = relu(bn2(acc1 + ze_b)) -> own rows of Az (C-layout scatter)
  #pragma unroll
  for (int t = 0; t < 8; ++t) {
    int c = t * 16 + ln;
    float zb = ze_b[c];
    float gg = ze_bn2[c], bb = ze_bn2[128 + c], mm = ze_bn2[256 + c], vv = ze_bn2[384 + c];
    #pragma unroll
    for (int r = 0; r < 4; ++r)
      Az[16 * wv + q * 4 + r][c] = f2b(fmaxf(0.f, bnf(acc1[t][r] + zb, gg, bb, mm, vv)));
  }
  __builtin_amdgcn_wave_barrier();
  // ---- GEMM2: acc2 += Az(z) @ WpSw
  #pragma unroll
  for (int kc = 0; kc < 4; ++kc) {
    short8 af = *(const short8*)&Az[16 * wv + ln][kc * 32 + q * 8];
    #pragma unroll
    for (int t = 0; t < 8; ++t) {
      short8 bfr = *(const short8*)(WpSw + (((size_t)kc * 8 + t) * 64 + lane) * 8);
      acc2[t] = __builtin_amdgcn_mfma_f32_16x16x32_bf16(af, bfr, acc2[t], 0, 0, 0);
    }
  }
  __builtin_amdgcn_wave_barrier();
  // ---- transpose acc2 -> own rows of Az as bf16
  #pragma unroll
  for (int t = 0; t < 8; ++t) {
    int c = t * 16 + ln;
    #pragma unroll
    for (int r = 0; r < 4; ++r)
      Az[16 * wv + q * 4 + r][c] = f2b(acc2[t][r]);
  }
  __builtin_amdgcn_wave_barrier();
  // ---- epilogue: lane -> edge (p*4+q) of own wave, cols ln*8..+7; f32 atomics
  #pragma unroll
  for (int p = 0; p < 4; ++p) {
    int el = 16 * wv + p * 4 + q;
    int e = e0 + el;
    int s = src[e], d2 = dst[e];
    U8 mm; mm.u = *(const uint4*)&Az[el][ln * 8];
    U8 hh; hh.u = ((const uint4*)h_in)[(size_t)s * 16 + ln];
    float* ap = agg + (size_t)d2 * Dd + ln * 8;
    #pragma unroll
    for (int j = 0; j < 8; ++j) {
      float v = fmaxf(0.f, b2f(mm.h[j]) + b2f(hh.h[j]));
      atomicAdd(ap + j, v);
    }
  }
}

// -------- fused node MLP, barrier-free MFMA --------
__global__ __launch_bounds__(256) void k_mlp_fused(
    const bf16* __restrict__ h_in, const float* __restrict__ agg,
    const float* __restrict__ eps_arr, int l,
    const bf16* __restrict__ W1sw, const float* __restrict__ b1, const float* __restrict__ bn,
    const bf16* __restrict__ W2sw, const float* __restrict__ b2, const float* __restrict__ bnp,
    int is_last, bf16* __restrict__ out_b, float* __restrict__ out_f) {
  __shared__ bf16 R[4][16][280];
  int tid = threadIdx.x;
  int lane = tid & 63, wv = tid >> 6;
  int q = lane >> 4, ln = lane & 15;
  int r0 = blockIdx.x * 64;
  float epsv = 1.0f + eps_arr[l];
  {
    int r = lane >> 2, cc = lane & 3;
    int row = r0 + 16 * wv + r;
    #pragma unroll
    for (int u = 0; u < 4; ++u) {
      int cb = cc * 4 + u;
      U8 o;
      if (row < Nn) {
        U8 hh; hh.u = ((const uint4*)h_in)[row * 16 + cb];
        float4 g0 = ((const float4*)agg)[row * 32 + cb * 2];
        float4 g1 = ((const float4*)agg)[row * 32 + cb * 2 + 1];
        o.h[0] = f2b(epsv * b2f(hh.h[0]) + g0.x); o.h[1] = f2b(epsv * b2f(hh.h[1]) + g0.y);
        o.h[2] = f2b(epsv * b2f(hh.h[2]) + g0.z); o.h[3] = f2b(epsv * b2f(hh.h[3]) + g0.w);
        o.h[4] = f2b(epsv * b2f(hh.h[4]) + g1.x); o.h[5] = f2b(epsv * b2f(hh.h[5]) + g1.y);
        o.h[6] = f2b(epsv * b2f(hh.h[6]) + g1.z); o.h[7] = f2b(epsv * b2f(hh.h[7]) + g1.w);
      } else {
        o.u.x = o.u.y = o.u.z = o.u.w = 0;
      }
      *(uint4*)&R[wv][r][cb * 8] = o.u;
    }
  }
  __builtin_amdgcn_wave_barrier();
  floatx4 acc1[16] = {};
  #pragma unroll
  for (int kc = 0; kc < 4; ++kc) {
    short8 af = *(const short8*)&R[wv][ln][kc * 32 + q * 8];
    #pragma unroll
    for (int t = 0; t < 16; ++t) {
      short8 bfr = *(const short8*)(W1sw + (size_t)l * 32768 + (((size_t)kc * 16 + t) * 64 + lane) * 8);
      acc1[t] = __builtin_amdgcn_mfma_f32_16x16x32_bf16(af, bfr, acc1[t], 0, 0, 0);
    }
  }
  #pragma unroll
  for (int t = 0; t < 16; ++t) {
    int c = t * 16 + ln;
    float b1v = b1[c];
    float gg = bn[c], bb = bn[256 + c], mm = bn[512 + c], vv = bn[768 + c];
    #pragma unroll
    for (int r = 0; r < 4; ++r)
      R[wv][q * 4 + r][c] = f2b(fmaxf(0.f, bnf(acc1[t][r] + b1v, gg, bb, mm, vv)));
  }
  __builtin_amdgcn_wave_barrier();
  floatx4 acc2[8] = {};
  #pragma unroll
  for (int kc = 0; kc < 8; ++kc) {
    short8 af = *(const short8*)&R[wv][ln][kc * 32 + q * 8];
    #pragma unroll
    for (int t = 0; t < 8; ++t) {
      short8 bfr = *(const short8*)(W2sw + (size_t)l * 32768 + (((size_t)kc * 8 + t) * 64 + lane) * 8);
      acc2[t] = __builtin_amdgcn_mfma_f32_16x16x32_bf16(af, bfr, acc2[t], 0, 0, 0);
    }
  }
  #pragma unroll
  for (int t = 0; t < 8; ++t) {
    int c = t * 16 + ln;
    float bv = b2[c];
    float gg = bnp[c], bb = bnp[128 + c], mm = bnp[256 + c], vv = bnp[384 + c];
    #pragma unroll
    for (int r = 0; r < 4; ++r) {
      int row = r0 + 16 * wv + q * 4 + r;
      if (row < Nn) {
        float x = bnf(acc2[t][r] + bv, gg, bb, mm, vv);
        if (is_last) out_f[(size_t)row * Dd + c] = x;
        else         out_b[(size_t)row * Dd + c] = f2b(fmaxf(0.f, x));
      }
    }
  }
}

// -------- vt = segment_sum(h_in, batch) --------
__global__ void k_vt_sum(const bf16* __restrict__ h_in, const int* __restrict__ batch,
                         float* __restrict__ vt) {
  int d = threadIdx.x;
  int chunk = (Nn + gridDim.x - 1) / gridDim.x;
  int r0 = blockIdx.x * chunk;
  int r1 = min(r0 + chunk, Nn);
  if (r0 >= r1) return;
  float acc = 0.f;
  int cur = batch[r0];
  for (int r = r0; r < r1; ++r) {
    int g = batch[r];
    if (g != cur) { atomicAdd(&vt[cur * Dd + d], acc); acc = 0.f; cur = g; }
    acc += b2f(h_in[r * Dd + d]);
  }
  atomicAdd(&vt[cur * Dd + d], acc);
}

// -------- virtual-node MLP (tiny) --------
__global__ __launch_bounds__(256) void k_vn_mlp(
    float* __restrict__ vn, const float* __restrict__ vt,
    const float* __restrict__ W1, const float* __restrict__ b1, const float* __restrict__ bn1,
    const float* __restrict__ W2, const float* __restrict__ b2, const float* __restrict__ bn2) {
  __shared__ float row[128];
  __shared__ float trow[256];
  int g = blockIdx.x;
  int tid = threadIdx.x;
  if (tid < 128) row[tid] = vt[g * Dd + tid] + vn[g * Dd + tid];
  __syncthreads();
  float acc = 0.f;
  for (int k = 0; k < 128; ++k) acc += row[k] * W1[k * 256 + tid];
  acc += b1[tid];
  trow[tid] = fmaxf(0.f, bnf(acc, bn1[tid], bn1[256 + tid], bn1[512 + tid], bn1[768 + tid]));
  __syncthreads();
  if (tid < 128) {
    float acc2 = 0.f;
    for (int k = 0; k < 256; ++k) acc2 += trow[k] * W2[k * Dd + tid];
    acc2 += b2[tid];
    vn[g * Dd + tid] = fmaxf(0.f, bnf(acc2, bn2[tid], bn2[128 + tid], bn2[256 + tid], bn2[384 + tid]));
  }
}

extern "C" void kernel_launch(void* const* d_in, const int* in_sizes, int n_in,
                              void* d_out, int out_size, void* d_ws, size_t ws_size,
                              hipStream_t stream) {
  const int*   x_node    = (const int*)  d_in[0];
  const int*   edge_idx  = (const int*)  d_in[1];
  const float* edge_attr = (const float*)d_in[2];
  const int*   batch     = (const int*)  d_in[3];
  const int*   pos_index = (const int*)  d_in[4];
  const float* pos_enc   = (const float*)d_in[5];
  const int*   pos_batch = (const int*)  d_in[6];
  const float* node_emb  = (const float*)d_in[7];
  const float* z_init    = (const float*)d_in[8];
  const float* ze_bn1    = (const float*)d_in[9];
  const float* ze_W      = (const float*)d_in[10];
  const float* ze_b      = (const float*)d_in[11];
  const float* ze_bn2    = (const float*)d_in[12];
  const float* vn_emb    = (const float*)d_in[13];
  const float* conv_We   = (const float*)d_in[14];
  const float* conv_be   = (const float*)d_in[15];
  const float* conv_Wp   = (const float*)d_in[16];
  const float* conv_bp   = (const float*)d_in[17];
  const float* conv_W1   = (const float*)d_in[18];
  const float* conv_b1   = (const float*)d_in[19];
  const float* conv_bn   = (const float*)d_in[20];
  const float* conv_W2   = (const float*)d_in[21];
  const float* conv_b2   = (const float*)d_in[22];
  const float* conv_eps  = (const float*)d_in[23];
  const float* layer_bn  = (const float*)d_in[24];
  const float* vn_W1     = (const float*)d_in[25];
  const float* vn_b1     = (const float*)d_in[26];
  const float* vn_bn1    = (const float*)d_in[27];
  const float* vn_W2     = (const float*)d_in[28];
  const float* vn_b2     = (const float*)d_in[29];
  const float* vn_bn2    = (const float*)d_in[30];

  // workspace (~80.0 MB) — R6 layout (f32 agg)
  char* wb = (char*)d_ws;
  bf16*  h_in   = (bf16*)(wb);                      // N*128 bf16
  float* agg    = (float*)(wb + 25600000);          // N*128 f32
  float* vn     = (float*)(wb + 76800000);          // G*128 f32
  float* vt     = (float*)(wb + 76865536);          // G*128 f32
  int*   estart = (int*)  (wb + 76931072);          // (E+1) int
  bf16*  zeWsw  = (bf16*) (wb + 79491088);
  bf16*  WpSw   = (bf16*) (wb + 79523856);
  bf16*  WeSw   = (bf16*) (wb + 79622160);
  bf16*  W1sw   = (bf16*) (wb + 79646736);
  bf16*  W2sw   = (bf16*) (wb + 79843344);

  const int* src = edge_idx;
  const int* dst = edge_idx + Ee;

  k_estart<<<(Ee + 256) / 256, 256, 0, stream>>>(pos_batch, estart);
  k_prep<<<(98304 + 255) / 256, 256, 0, stream>>>(ze_W, conv_Wp, conv_We, conv_be, conv_bp,
                                                  conv_W1, conv_W2,
                                                  zeWsw, WpSw, WeSw, W1sw, W2sw);
  k_init_vn<<<(Gg * 128 + 255) / 256, 256, 0, stream>>>(vn_emb, vn);

  int hblocks = (Nn * 16 + 255) / 256;
  int mblocks = (Nn + 63) / 64;
  for (int l = 0; l < Ll; ++l) {
    if (l == 0) k_hin0<<<hblocks, 256, 0, stream>>>(x_node, node_emb, vn, batch, h_in);
    else        k_hin <<<hblocks, 256, 0, stream>>>(vn, batch, h_in);
    hipMemsetAsync(agg, 0, (size_t)Nn * 128 * 4, stream);
    k_edge_fused<<<Ee / 64, 256, 0, stream>>>(estart, pos_index, pos_enc, z_init,
        ze_bn1, zeWsw, ze_b, ze_bn2,
        edge_attr, src, dst, h_in,
        WpSw + (size_t)l * 16384, WeSw + (size_t)l * 4096, agg);
    if (l < Ll - 1) {
      hipMemsetAsync(vt, 0, (size_t)Gg * 128 * 4, stream);
      k_vt_sum<<<1024, 128, 0, stream>>>(h_in, batch, vt);
      k_vn_mlp<<<Gg, 256, 0, stream>>>(vn, vt,
          vn_W1 + (size_t)l * 128 * 256, vn_b1 + l * 256, vn_bn1 + (size_t)l * 4 * 256,
          vn_W2 + (size_t)l * 256 * 128, vn_b2 + l * 128, vn_bn2 + (size_t)l * 4 * 128);
    }
    k_mlp_fused<<<mblocks, 256, 0, stream>>>(h_in, agg, conv_eps, l,
        W1sw, conv_b1 + l * 256, conv_bn + (size_t)l * 4 * 256,
        W2sw, conv_b2 + l * 128, layer_bn + (size_t)l * 4 * 128,
        (l == Ll - 1) ? 1 : 0, h_in, (float*)d_out);
  }
}

// Round 10
// 1901.186 us; speedup vs baseline: 3.9765x; 3.9765x over previous
//
#include <hip/hip_runtime.h>
#include <hip/hip_bf16.h>

typedef __hip_bfloat16 bf16;
typedef __attribute__((ext_vector_type(8))) short short8;
typedef __attribute__((ext_vector_type(4))) float floatx4;

constexpr int Nn = 100000;   // nodes
constexpr int Ee = 640000;   // edges
constexpr int Pp = 640000;   // pos entries
constexpr int Gg = 128;      // graphs
constexpr int Ll = 3;        // layers
#define Dd 128
#define BN_EPS 1e-5f

__device__ __forceinline__ float b2f(bf16 x) { return __bfloat162float(x); }
__device__ __forceinline__ bf16 f2b(float x) { return __float2bfloat16(x); }

union U8 { uint4 u; bf16 h[8]; };

__device__ __forceinline__ float bnf(float x, float g, float b, float m, float v) {
  return (x - m) * (1.0f / sqrtf(v + BN_EPS)) * g + b;
}

// -------- estart[e] = lower_bound(pos_batch, e) --------
__global__ void k_estart(const int* __restrict__ pos_batch, int* __restrict__ estart) {
  int e = blockIdx.x * blockDim.x + threadIdx.x;
  if (e > Ee) return;
  int lo = 0, hi = Pp;
  while (lo < hi) { int mid = (lo + hi) >> 1; if (pos_batch[mid] < e) lo = mid + 1; else hi = mid; }
  estart[e] = lo;
}

// -------- pre-swizzle weights into MFMA B-fragment order: [kc][t][lane][8] --------
__global__ void k_prep(const float* __restrict__ zeW, const float* __restrict__ Wp,
                       const float* __restrict__ We, const float* __restrict__ be,
                       const float* __restrict__ bp,
                       const float* __restrict__ W1, const float* __restrict__ W2,
                       bf16* __restrict__ zeWsw, bf16* __restrict__ WpSw,
                       bf16* __restrict__ WeSw, bf16* __restrict__ W1sw,
                       bf16* __restrict__ W2sw) {
  int gid = blockIdx.x * blockDim.x + threadIdx.x;
  if (gid < 16384) {
    int i = gid;
    int j = i & 7, lane = (i >> 3) & 63, t = (i >> 9) & 7, kc = i >> 12;
    int k = kc * 32 + ((lane >> 4) * 8) + j, n = t * 16 + (lane & 15);
    zeWsw[i] = f2b(zeW[k * 128 + n]);
  }
  if (gid < 49152) {
    int l = gid / 16384, i = gid % 16384;
    int j = i & 7, lane = (i >> 3) & 63, t = (i >> 9) & 7, kc = i >> 12;
    int k = kc * 32 + ((lane >> 4) * 8) + j, n = t * 16 + (lane & 15);
    WpSw[gid] = f2b(Wp[l * 16384 + k * 128 + n]);
  }
  if (gid < 12288) {
    int l = gid / 4096, i = gid % 4096;
    int j = i & 7, lane = (i >> 3) & 63, t = i >> 9;
    int k = ((lane >> 4) * 8) + j, n = t * 16 + (lane & 15);
    float v = 0.f;
    if (k < 7) v = We[l * 896 + k * 128 + n];
    else if (k == 7) v = be[l * 128 + n] + bp[l * 128 + n];
    WeSw[gid] = f2b(v);
  }
  if (gid < 98304) {
    int l = gid / 32768, i = gid % 32768;
    int j = i & 7, lane = (i >> 3) & 63, t = (i >> 9) & 15, kc = i >> 13;
    int k = kc * 32 + ((lane >> 4) * 8) + j, n = t * 16 + (lane & 15);
    W1sw[gid] = f2b(W1[l * 32768 + k * 256 + n]);
  }
  if (gid < 98304) {
    int l = gid / 32768, i = gid % 32768;
    int j = i & 7, lane = (i >> 3) & 63, t = (i >> 9) & 7, kc = i >> 12;
    int k = kc * 32 + ((lane >> 4) * 8) + j, n = t * 16 + (lane & 15);
    W2sw[gid] = f2b(W2[l * 32768 + k * 128 + n]);
  }
}

__global__ void k_init_vn(const float* __restrict__ vn_emb, float* __restrict__ vn) {
  int gid = blockIdx.x * blockDim.x + threadIdx.x;
  if (gid >= Gg * 128) return;
  vn[gid] = vn_emb[gid & 127];
}

// -------- h_in = node_emb[x_node] + vn[batch]  (layer 0) --------
__global__ void k_hin0(const int* __restrict__ x_node, const float* __restrict__ node_emb,
                       const float* __restrict__ vn, const int* __restrict__ batch,
                       bf16* __restrict__ h_in) {
  int gid = blockIdx.x * blockDim.x + threadIdx.x;
  if (gid >= Nn * 16) return;
  int n = gid >> 4, c = gid & 15;
  int x = x_node[n], b = batch[n];
  float4 a0 = ((const float4*)node_emb)[x * 32 + c * 2];
  float4 a1 = ((const float4*)node_emb)[x * 32 + c * 2 + 1];
  float4 v0 = ((const float4*)vn)[b * 32 + c * 2];
  float4 v1 = ((const float4*)vn)[b * 32 + c * 2 + 1];
  U8 o;
  o.h[0] = f2b(a0.x + v0.x); o.h[1] = f2b(a0.y + v0.y);
  o.h[2] = f2b(a0.z + v0.z); o.h[3] = f2b(a0.w + v0.w);
  o.h[4] = f2b(a1.x + v1.x); o.h[5] = f2b(a1.y + v1.y);
  o.h[6] = f2b(a1.z + v1.z); o.h[7] = f2b(a1.w + v1.w);
  ((uint4*)h_in)[gid] = o.u;
}

// -------- h_in += vn[batch]  (layers 1..) --------
__global__ void k_hin(const float* __restrict__ vn, const int* __restrict__ batch,
                      bf16* __restrict__ h_in) {
  int gid = blockIdx.x * blockDim.x + threadIdx.x;
  if (gid >= Nn * 16) return;
  int n = gid >> 4, c = gid & 15;
  U8 a; a.u = ((const uint4*)h_in)[gid];
  int b = batch[n];
  float4 v0 = ((const float4*)vn)[b * 32 + c * 2];
  float4 v1 = ((const float4*)vn)[b * 32 + c * 2 + 1];
  U8 o;
  o.h[0] = f2b(b2f(a.h[0]) + v0.x); o.h[1] = f2b(b2f(a.h[1]) + v0.y);
  o.h[2] = f2b(b2f(a.h[2]) + v0.z); o.h[3] = f2b(b2f(a.h[3]) + v0.w);
  o.h[4] = f2b(b2f(a.h[4]) + v1.x); o.h[5] = f2b(b2f(a.h[5]) + v1.y);
  o.h[6] = f2b(b2f(a.h[6]) + v1.z); o.h[7] = f2b(b2f(a.h[7]) + v1.w);
  ((uint4*)h_in)[gid] = o.u;
}

// -------- fused edge kernel: MFMA + LDS h_in gather + cacheline-coalesced f32 atomics --
__global__ __launch_bounds__(256, 4) void k_edge_fused(
    const int* __restrict__ estart, const int* __restrict__ pos_index,
    const float* __restrict__ pos_enc, const float* __restrict__ z_init,
    const float* __restrict__ ze_bn1, const bf16* __restrict__ zeWsw,
    const float* __restrict__ ze_b, const float* __restrict__ ze_bn2,
    const float* __restrict__ eattr, const int* __restrict__ src,
    const int* __restrict__ dst, const bf16* __restrict__ h_in,
    const bf16* __restrict__ WpSw, const bf16* __restrict__ WeSw,
    float* __restrict__ agg) {
  __shared__ bf16 Az[64][136];   // wave-exclusive rows (zpool -> z -> h_in tile)
  __shared__ bf16 EaB[64][40];
  int tid = threadIdx.x;
  int lane = tid & 63, wv = tid >> 6;
  int q = lane >> 4, ln = lane & 15;
  int e0 = blockIdx.x * 64;

  // ---- stage EaB (wave-exclusive rows)
  {
    int r = lane >> 2, c0 = (lane & 3) * 8;
    int e = e0 + 16 * wv + r;
    U8 o;
    #pragma unroll
    for (int j = 0; j < 8; ++j) {
      int c = c0 + j;
      float v = 0.f;
      if (c < 7) v = eattr[(size_t)e * 7 + c];
      else if (c == 7) v = 1.0f;
      o.h[j] = f2b(v);
    }
    *(uint4*)&EaB[16 * wv + r][c0] = o.u;
  }
  // ---- zpool gather + bn1/relu -> Az (wave-exclusive rows)
  {
    int r = lane >> 2, cc = lane & 3;
    int e = e0 + 16 * wv + r;
    int ps = estart[e], pe = estart[e + 1];
    float acc[32];
    #pragma unroll
    for (int j = 0; j < 32; ++j) acc[j] = 0.f;
    for (int p = ps; p < pe; ++p) {
      int idx = pos_index[p];
      float w = pos_enc[p];
      #pragma unroll
      for (int qq = 0; qq < 8; ++qq) {
        float4 z4 = ((const float4*)z_init)[idx * 32 + cc * 8 + qq];
        acc[qq * 4 + 0] = fmaf(w, z4.x, acc[qq * 4 + 0]);
        acc[qq * 4 + 1] = fmaf(w, z4.y, acc[qq * 4 + 1]);
        acc[qq * 4 + 2] = fmaf(w, z4.z, acc[qq * 4 + 2]);
        acc[qq * 4 + 3] = fmaf(w, z4.w, acc[qq * 4 + 3]);
      }
    }
    #pragma unroll
    for (int qq = 0; qq < 4; ++qq) {
      U8 o;
      #pragma unroll
      for (int jj = 0; jj < 2; ++jj) {
        int col = cc * 32 + qq * 8 + jj * 4;
        float4 g = *(const float4*)&ze_bn1[col];
        float4 b = *(const float4*)&ze_bn1[128 + col];
        float4 m = *(const float4*)&ze_bn1[256 + col];
        float4 v = *(const float4*)&ze_bn1[384 + col];
        o.h[jj * 4 + 0] = f2b(fmaxf(0.f, bnf(acc[qq * 8 + jj * 4 + 0], g.x, b.x, m.x, v.x)));
        o.h[jj * 4 + 1] = f2b(fmaxf(0.f, bnf(acc[qq * 8 + jj * 4 + 1], g.y, b.y, m.y, v.y)));
        o.h[jj * 4 + 2] = f2b(fmaxf(0.f, bnf(acc[qq * 8 + jj * 4 + 2], g.z, b.z, m.z, v.z)));
        o.h[jj * 4 + 3] = f2b(fmaxf(0.f, bnf(acc[qq * 8 + jj * 4 + 3], g.w, b.w, m.w, v.w)));
      }
      *(uint4*)&Az[16 * wv + r][cc * 32 + qq * 8] = o.u;
    }
  }
  __builtin_amdgcn_wave_barrier();

  // ---- GEMM0: acc2 = EaB @ WeSw (K=32 incl. bias col)
  floatx4 acc2[8] = {};
  {
    short8 af0 = *(const short8*)&EaB[16 * wv + ln][q * 8];
    #pragma unroll
    for (int t = 0; t < 8; ++t) {
      short8 bfr = *(const short8*)(WeSw + ((size_t)t * 64 + lane) * 8);
      acc2[t] = __builtin_amdgcn_mfma_f32_16x16x32_bf16(af0, bfr, acc2[t], 0, 0, 0);
    }
  }
  // ---- GEMM1: acc1 = Az @ zeWsw
  floatx4 acc1[8] = {};
  #pragma unroll
  for (int kc = 0; kc < 4; ++kc) {
    short8 af = *(const short8*)&Az[16 * wv + ln][kc * 32 + q * 8];
    #pragma unroll
    for (int t = 0; t < 8; ++t) {
      short8 bfr = *(const short8*)(zeWsw + (((size_t)kc * 8 + t) * 64 + lane) * 8);
      acc1[t] = __builtin_amdgcn_mfma_f32_16x16x32_bf16(af, bfr, acc1[t], 0, 0, 0);
    }
  }
  // ---- z = relu(bn2(acc1 + ze_b)) -> own rows of Az (C-layout scatter)
  #pragma unroll
  for (int t = 0; t < 8; ++t) {
    int c = t * 16 + ln;
    float zb = ze_b[c];
    float gg = ze_bn2[c], bb = ze_bn2[128 + c], mm = ze_bn2[256 + c], vv = ze_bn2[384 + c];
    #pragma unroll
    for (int r = 0; r < 4; ++r)
      Az[16 * wv + q * 4 + r][c] = f2b(fmaxf(0.f, bnf(acc1[t][r] + zb, gg, bb, mm, vv)));
  }
  __builtin_amdgcn_wave_barrier();
  // ---- GEMM2: acc2 += Az(z) @ WpSw
  #pragma unroll
  for (int kc = 0; kc < 4; ++kc) {
    short8 af = *(const short8*)&Az[16 * wv + ln][kc * 32 + q * 8];
    #pragma unroll
    for (int t = 0; t < 8; ++t) {
      short8 bfr = *(const short8*)(WpSw + (((size_t)kc * 8 + t) * 64 + lane) * 8);
      acc2[t] = __builtin_amdgcn_mfma_f32_16x16x32_bf16(af, bfr, acc2[t], 0, 0, 0);
    }
  }
  __builtin_amdgcn_wave_barrier();
  // ---- coalesced h_in gather into own rows of Az (GEMM2 reads complete first; in-wave order)
  #pragma unroll
  for (int p = 0; p < 4; ++p) {
    int el = 16 * wv + p * 4 + q;
    int s = src[e0 + el];
    uint4 hh = ((const uint4*)h_in)[(size_t)s * 16 + ln];
    *(uint4*)&Az[el][ln * 8] = hh;
  }
  __builtin_amdgcn_wave_barrier();
  // ---- epilogue: R6 atomic pattern — quad covers one full 64B cacheline per instruction
  #pragma unroll
  for (int r = 0; r < 4; ++r) {
    int el = 16 * wv + q * 4 + r;
    int d2 = dst[e0 + el];
    float* ap = agg + (size_t)d2 * Dd;
    #pragma unroll
    for (int t = 0; t < 8; ++t) {
      int c = t * 16 + ln;
      float v = fmaxf(0.f, acc2[t][r] + b2f(Az[el][c]));
      atomicAdd(ap + c, v);
    }
  }
}

// -------- fused node MLP, barrier-free MFMA --------
__global__ __launch_bounds__(256) void k_mlp_fused(
    const bf16* __restrict__ h_in, const float* __restrict__ agg,
    const float* __restrict__ eps_arr, int l,
    const bf16* __restrict__ W1sw, const float* __restrict__ b1, const float* __restrict__ bn,
    const bf16* __restrict__ W2sw, const float* __restrict__ b2, const float* __restrict__ bnp,
    int is_last, bf16* __restrict__ out_b, float* __restrict__ out_f) {
  __shared__ bf16 R[4][16][280];
  int tid = threadIdx.x;
  int lane = tid & 63, wv = tid >> 6;
  int q = lane >> 4, ln = lane & 15;
  int r0 = blockIdx.x * 64;
  float epsv = 1.0f + eps_arr[l];
  {
    int r = lane >> 2, cc = lane & 3;
    int row = r0 + 16 * wv + r;
    #pragma unroll
    for (int u = 0; u < 4; ++u) {
      int cb = cc * 4 + u;
      U8 o;
      if (row < Nn) {
        U8 hh; hh.u = ((const uint4*)h_in)[row * 16 + cb];
        float4 g0 = ((const float4*)agg)[row * 32 + cb * 2];
        float4 g1 = ((const float4*)agg)[row * 32 + cb * 2 + 1];
        o.h[0] = f2b(epsv * b2f(hh.h[0]) + g0.x); o.h[1] = f2b(epsv * b2f(hh.h[1]) + g0.y);
        o.h[2] = f2b(epsv * b2f(hh.h[2]) + g0.z); o.h[3] = f2b(epsv * b2f(hh.h[3]) + g0.w);
        o.h[4] = f2b(epsv * b2f(hh.h[4]) + g1.x); o.h[5] = f2b(epsv * b2f(hh.h[5]) + g1.y);
        o.h[6] = f2b(epsv * b2f(hh.h[6]) + g1.z); o.h[7] = f2b(epsv * b2f(hh.h[7]) + g1.w);
      } else {
        o.u.x = o.u.y = o.u.z = o.u.w = 0;
      }
      *(uint4*)&R[wv][r][cb * 8] = o.u;
    }
  }
  __builtin_amdgcn_wave_barrier();
  floatx4 acc1[16] = {};
  #pragma unroll
  for (int kc = 0; kc < 4; ++kc) {
    short8 af = *(const short8*)&R[wv][ln][kc * 32 + q * 8];
    #pragma unroll
    for (int t = 0; t < 16; ++t) {
      short8 bfr = *(const short8*)(W1sw + (size_t)l * 32768 + (((size_t)kc * 16 + t) * 64 + lane) * 8);
      acc1[t] = __builtin_amdgcn_mfma_f32_16x16x32_bf16(af, bfr, acc1[t], 0, 0, 0);
    }
  }
  #pragma unroll
  for (int t = 0; t < 16; ++t) {
    int c = t * 16 + ln;
    float b1v = b1[c];
    float gg = bn[c], bb = bn[256 + c], mm = bn[512 + c], vv = bn[768 + c];
    #pragma unroll
    for (int r = 0; r < 4; ++r)
      R[wv][q * 4 + r][c] = f2b(fmaxf(0.f, bnf(acc1[t][r] + b1v, gg, bb, mm, vv)));
  }
  __builtin_amdgcn_wave_barrier();
  floatx4 acc2[8] = {};
  #pragma unroll
  for (int kc = 0; kc < 8; ++kc) {
    short8 af = *(const short8*)&R[wv][ln][kc * 32 + q * 8];
    #pragma unroll
    for (int t = 0; t < 8; ++t) {
      short8 bfr = *(const short8*)(W2sw + (size_t)l * 32768 + (((size_t)kc * 8 + t) * 64 + lane) * 8);
      acc2[t] = __builtin_amdgcn_mfma_f32_16x16x32_bf16(af, bfr, acc2[t], 0, 0, 0);
    }
  }
  #pragma unroll
  for (int t = 0; t < 8; ++t) {
    int c = t * 16 + ln;
    float bv = b2[c];
    float gg = bnp[c], bb = bnp[128 + c], mm = bnp[256 + c], vv = bnp[384 + c];
    #pragma unroll
    for (int r = 0; r < 4; ++r) {
      int row = r0 + 16 * wv + q * 4 + r;
      if (row < Nn) {
        float x = bnf(acc2[t][r] + bv, gg, bb, mm, vv);
        if (is_last) out_f[(size_t)row * Dd + c] = x;
        else         out_b[(size_t)row * Dd + c] = f2b(fmaxf(0.f, x));
      }
    }
  }
}

// -------- vt = segment_sum(h_in, batch) --------
__global__ void k_vt_sum(const bf16* __restrict__ h_in, const int* __restrict__ batch,
                         float* __restrict__ vt) {
  int d = threadIdx.x;
  int chunk = (Nn + gridDim.x - 1) / gridDim.x;
  int r0 = blockIdx.x * chunk;
  int r1 = min(r0 + chunk, Nn);
  if (r0 >= r1) return;
  float acc = 0.f;
  int cur = batch[r0];
  for (int r = r0; r < r1; ++r) {
    int g = batch[r];
    if (g != cur) { atomicAdd(&vt[cur * Dd + d], acc); acc = 0.f; cur = g; }
    acc += b2f(h_in[r * Dd + d]);
  }
  atomicAdd(&vt[cur * Dd + d], acc);
}

// -------- virtual-node MLP (tiny) --------
__global__ __launch_bounds__(256) void k_vn_mlp(
    float* __restrict__ vn, const float* __restrict__ vt,
    const float* __restrict__ W1, const float* __restrict__ b1, const float* __restrict__ bn1,
    const float* __restrict__ W2, const float* __restrict__ b2, const float* __restrict__ bn2) {
  __shared__ float row[128];
  __shared__ float trow[256];
  int g = blockIdx.x;
  int tid = threadIdx.x;
  if (tid < 128) row[tid] = vt[g * Dd + tid] + vn[g * Dd + tid];
  __syncthreads();
  float acc = 0.f;
  for (int k = 0; k < 128; ++k) acc += row[k] * W1[k * 256 + tid];
  acc += b1[tid];
  trow[tid] = fmaxf(0.f, bnf(acc, bn1[tid], bn1[256 + tid], bn1[512 + tid], bn1[768 + tid]));
  __syncthreads();
  if (tid < 128) {
    float acc2 = 0.f;
    for (int k = 0; k < 256; ++k) acc2 += trow[k] * W2[k * Dd + tid];
    acc2 += b2[tid];
    vn[g * Dd + tid] = fmaxf(0.f, bnf(acc2, bn2[tid], bn2[128 + tid], bn2[256 + tid], bn2[384 + tid]));
  }
}

extern "C" void kernel_launch(void* const* d_in, const int* in_sizes, int n_in,
                              void* d_out, int out_size, void* d_ws, size_t ws_size,
                              hipStream_t stream) {
  const int*   x_node    = (const int*)  d_in[0];
  const int*   edge_idx  = (const int*)  d_in[1];
  const float* edge_attr = (const float*)d_in[2];
  const int*   batch     = (const int*)  d_in[3];
  const int*   pos_index = (const int*)  d_in[4];
  const float* pos_enc   = (const float*)d_in[5];
  const int*   pos_batch = (const int*)  d_in[6];
  const float* node_emb  = (const float*)d_in[7];
  const float* z_init    = (const float*)d_in[8];
  const float* ze_bn1    = (const float*)d_in[9];
  const float* ze_W      = (const float*)d_in[10];
  const float* ze_b      = (const float*)d_in[11];
  const float* ze_bn2    = (const float*)d_in[12];
  const float* vn_emb    = (const float*)d_in[13];
  const float* conv_We   = (const float*)d_in[14];
  const float* conv_be   = (const float*)d_in[15];
  const float* conv_Wp   = (const float*)d_in[16];
  const float* conv_bp   = (const float*)d_in[17];
  const float* conv_W1   = (const float*)d_in[18];
  const float* conv_b1   = (const float*)d_in[19];
  const float* conv_bn   = (const float*)d_in[20];
  const float* conv_W2   = (const float*)d_in[21];
  const float* conv_b2   = (const float*)d_in[22];
  const float* conv_eps  = (const float*)d_in[23];
  const float* layer_bn  = (const float*)d_in[24];
  const float* vn_W1     = (const float*)d_in[25];
  const float* vn_b1     = (const float*)d_in[26];
  const float* vn_bn1    = (const float*)d_in[27];
  const float* vn_W2     = (const float*)d_in[28];
  const float* vn_b2     = (const float*)d_in[29];
  const float* vn_bn2    = (const float*)d_in[30];

  // workspace (~80.0 MB) — R6 layout (f32 agg)
  char* wb = (char*)d_ws;
  bf16*  h_in   = (bf16*)(wb);                      // N*128 bf16
  float* agg    = (float*)(wb + 25600000);          // N*128 f32
  float* vn     = (float*)(wb + 76800000);          // G*128 f32
  float* vt     = (float*)(wb + 76865536);          // G*128 f32
  int*   estart = (int*)  (wb + 76931072);          // (E+1) int
  bf16*  zeWsw  = (bf16*) (wb + 79491088);
  bf16*  WpSw   = (bf16*) (wb + 79523856);
  bf16*  WeSw   = (bf16*) (wb + 79622160);
  bf16*  W1sw   = (bf16*) (wb + 79646736);
  bf16*  W2sw   = (bf16*) (wb + 79843344);

  const int* src = edge_idx;
  const int* dst = edge_idx + Ee;

  k_estart<<<(Ee + 256) / 256, 256, 0, stream>>>(pos_batch, estart);
  k_prep<<<(98304 + 255) / 256, 256, 0, stream>>>(ze_W, conv_Wp, conv_We, conv_be, conv_bp,
                                                  conv_W1, conv_W2,
                                                  zeWsw, WpSw, WeSw, W1sw, W2sw);
  k_init_vn<<<(Gg * 128 + 255) / 256, 256, 0, stream>>>(vn_emb, vn);

  int hblocks = (Nn * 16 + 255) / 256;
  int mblocks = (Nn + 63) / 64;
  for (int l = 0; l < Ll; ++l) {
    if (l == 0) k_hin0<<<hblocks, 256, 0, stream>>>(x_node, node_emb, vn, batch, h_in);
    else        k_hin <<<hblocks, 256, 0, stream>>>(vn, batch, h_in);
    hipMemsetAsync(agg, 0, (size_t)Nn * 128 * 4, stream);
    k_edge_fused<<<Ee / 64, 256, 0, stream>>>(estart, pos_index, pos_enc, z_init,
        ze_bn1, zeWsw, ze_b, ze_bn2,
        edge_attr, src, dst, h_in,
        WpSw + (size_t)l * 16384, WeSw + (size_t)l * 4096, agg);
    if (l < Ll - 1) {
      hipMemsetAsync(vt, 0, (size_t)Gg * 128 * 4, stream);
      k_vt_sum<<<1024, 128, 0, stream>>>(h_in, batch, vt);
      k_vn_mlp<<<Gg, 256, 0, stream>>>(vn, vt,
          vn_W1 + (size_t)l * 128 * 256, vn_b1 + l * 256, vn_bn1 + (size_t)l * 4 * 256,
          vn_W2 + (size_t)l * 256 * 128, vn_b2 + l * 128, vn_bn2 + (size_t)l * 4 * 128);
    }
    k_mlp_fused<<<mblocks, 256, 0, stream>>>(h_in, agg, conv_eps, l,
        W1sw, conv_b1 + l * 256, conv_bn + (size_t)l * 4 * 256,
        W2sw, conv_b2 + l * 128, layer_bn + (size_t)l * 4 * 128,
        (l == Ll - 1) ? 1 : 0, h_in, (float*)d_out);
  }
}